// Round 12
// baseline (748.816 us; speedup 1.0000x reference)
//
#include <hip/hip_runtime.h>

typedef __attribute__((ext_vector_type(8))) __bf16 bf8;
typedef __attribute__((ext_vector_type(4))) __bf16 bf4;
typedef __attribute__((ext_vector_type(4))) float f32x4;

#define DEVI static __device__ __forceinline__
#define DEVM __device__ __forceinline__

// async global->LDS, 16B per lane. LDS dest must be linear in lane order.
DEVI void gload_lds16(const void* g, void* l) {
  __builtin_amdgcn_global_load_lds(
      (const __attribute__((address_space(1))) unsigned int*)g,
      (__attribute__((address_space(3))) unsigned int*)l, 16, 0, 0);
}

// counted vmcnt + hard scheduling fence (rule #18)
#define WAITV(N)                                             \
  asm volatile("s_waitcnt vmcnt(" #N ")" ::: "memory");      \
  __builtin_amdgcn_sched_barrier(0)
#define LGKM0()                                              \
  asm volatile("s_waitcnt lgkmcnt(0)" ::: "memory");         \
  __builtin_amdgcn_sched_barrier(0)
#define BARRIER()                      \
  __builtin_amdgcn_sched_barrier(0);   \
  __builtin_amdgcn_s_barrier();        \
  __builtin_amdgcn_sched_barrier(0)

// ---------------- f32 -> bf16 convert ----------------
__global__ __launch_bounds__(256) void cvt_kernel(const float* __restrict__ in,
                                                  __bf16* __restrict__ out, int n4) {
  int stride = gridDim.x * blockDim.x;
  for (int i = blockIdx.x * blockDim.x + threadIdx.x; i < n4; i += stride) {
    f32x4 v = reinterpret_cast<const f32x4*>(in)[i];
    bf4 o;
    o[0] = (__bf16)v[0]; o[1] = (__bf16)v[1]; o[2] = (__bf16)v[2]; o[3] = (__bf16)v[3];
    reinterpret_cast<bf4*>(out)[i] = o;
  }
}

// three weight matrices in one launch (grid 768: seg = blockIdx.x>>8)
__global__ __launch_bounds__(256) void cvt3_kernel(
    const float* __restrict__ a, const float* __restrict__ b, const float* __restrict__ c,
    __bf16* __restrict__ oa, __bf16* __restrict__ ob, __bf16* __restrict__ oc) {
  const int seg = blockIdx.x >> 8;
  const float* in = seg == 0 ? a : (seg == 1 ? b : c);
  __bf16* out = seg == 0 ? oa : (seg == 1 ? ob : oc);
  const int stride = 256 * 256;
  for (int i = (blockIdx.x & 255) * 256 + threadIdx.x; i < 262144; i += stride) {
    f32x4 v = reinterpret_cast<const f32x4*>(in)[i];
    bf4 o;
    o[0] = (__bf16)v[0]; o[1] = (__bf16)v[1]; o[2] = (__bf16)v[2]; o[3] = (__bf16)v[3];
    reinterpret_cast<bf4*>(out)[i] = o;
  }
}

// ---------------- GEMM core: 256x256 tile, 8 waves, 2-deep counted-vmcnt pipeline ----
// (proven round 9/10 structure, factored so both kernels share it)
struct GemmCore {
  const __bf16* Ab;
  const __bf16* Bb;
  __bf16* As0; __bf16* Bs0; __bf16* As1; __bf16* Bs1;
  int tid, lane, wr, wc, lr, khi, srow, scc;

  DEVM void stage(const __bf16* gb, __bf16* lds, int kt) const {
#pragma unroll
    for (int i = 0; i < 4; ++i)
      gload_lds16(gb + (size_t)(i * 64 + srow) * 1024 + kt * 64 + scc * 8,
                  lds + i * 4096 + tid * 8);
  }
  DEVM void compute(const __bf16* As, const __bf16* Bs, f32x4 acc[8][4]) const {
    __builtin_amdgcn_s_setprio(1);
#pragma unroll
    for (int kk = 0; kk < 2; ++kk) {
      const int ck = ((kk * 4 + khi) ^ (lr & 7)) * 8;
      bf8 a[8], b[4];
#pragma unroll
      for (int mi = 0; mi < 8; ++mi)
        a[mi] = *reinterpret_cast<const bf8*>(&As[(wr * 128 + mi * 16 + lr) * 64 + ck]);
#pragma unroll
      for (int ni = 0; ni < 4; ++ni)
        b[ni] = *reinterpret_cast<const bf8*>(&Bs[(wc * 64 + ni * 16 + lr) * 64 + ck]);
#pragma unroll
      for (int mi = 0; mi < 8; ++mi)
#pragma unroll
        for (int ni = 0; ni < 4; ++ni)
          acc[mi][ni] = __builtin_amdgcn_mfma_f32_16x16x32_bf16(a[mi], b[ni], acc[mi][ni], 0, 0, 0);
    }
    __builtin_amdgcn_s_setprio(0);
  }
  DEVM void run(f32x4 acc[8][4]) const {
    stage(Ab, As0, 0); stage(Bb, Bs0, 0);
    stage(Ab, As1, 1); stage(Bb, Bs1, 1);
    for (int it = 0; it < 7; ++it) {
      WAITV(8);
      BARRIER();
      compute(As0, Bs0, acc);
      BARRIER();
      stage(Ab, As0, 2 * it + 2); stage(Bb, Bs0, 2 * it + 2);
      WAITV(8);
      BARRIER();
      compute(As1, Bs1, acc);
      BARRIER();
      stage(Ab, As1, 2 * it + 3); stage(Bb, Bs1, 2 * it + 3);
    }
    WAITV(8);
    BARRIER();
    compute(As0, Bs0, acc);
    WAITV(0);
    BARRIER();
    compute(As1, Bs1, acc);
  }
};

// ---------------- merged input projections: z=0 fhead, z=1 ftail, z=2 fvT ----------------
// grid (64,4,3): linear id = bm + 64*(bn+4*z) -> XCD = bm%8 (A-panel affinity;
// xkv panels shared by z=1,2 on the same XCD -> L2 hits).
__global__ __launch_bounds__(512, 2) void gemm_inproj(
    const __bf16* __restrict__ xq, const __bf16* __restrict__ xkv,
    const __bf16* __restrict__ Wh, const __bf16* __restrict__ Wv,
    const float* __restrict__ bh, const float* __restrict__ bv,
    const float* __restrict__ rel,
    __bf16* __restrict__ fhead, __bf16* __restrict__ ftail, __bf16* __restrict__ fvT) {
  __shared__ alignas(16) __bf16 As0[256 * 64];
  __shared__ alignas(16) __bf16 Bs0[256 * 64];
  __shared__ alignas(16) __bf16 As1[256 * 64];
  __shared__ alignas(16) __bf16 Bs1[256 * 64];
  const int tid = threadIdx.x;
  const int lane = tid & 63;
  const int wave = tid >> 6;
  const int bm = blockIdx.x, bn = blockIdx.y, z = blockIdx.z;

  const __bf16* A = (z == 0) ? xq : xkv;
  const __bf16* Bw = (z == 2) ? Wv : Wh;
  const float* bias = (z == 2) ? bv : bh;
  __bf16* obf = (z == 0) ? fhead : (z == 1) ? ftail : fvT;

  GemmCore core{A + (size_t)bm * 256 * 1024, Bw + (size_t)bn * 256 * 1024,
                As0, Bs0, As1, Bs1,
                tid, lane, wave >> 2, wave & 3, lane & 15, lane >> 4,
                tid >> 3, (tid & 7) ^ ((tid >> 3) & 7)};

  f32x4 acc[8][4];
#pragma unroll
  for (int mi = 0; mi < 8; ++mi)
#pragma unroll
    for (int ni = 0; ni < 4; ++ni)
#pragma unroll
      for (int e = 0; e < 4; ++e) acc[mi][ni][e] = 0.f;

  core.run(acc);

  const int wr = wave >> 2, wc = wave & 3, lr = lane & 15, khi = lane >> 4;
#pragma unroll
  for (int mi = 0; mi < 8; ++mi) {
#pragma unroll
    for (int ni = 0; ni < 4; ++ni) {
      const int n = bn * 256 + wc * 64 + ni * 16 + lr;
#pragma unroll
      for (int r = 0; r < 4; ++r) {
        const int m = bm * 256 + wr * 128 + mi * 16 + khi * 4 + r;
        float v = acc[mi][ni][r] + bias[n];
        if (z < 2) {
          v *= rel[n];
          size_t idx = ((size_t)((m >> 9) * 8 + (n >> 7))) * 65536 +
                       (size_t)(m & 511) * 128 + (n & 127);
          obf[idx] = (__bf16)v;
        } else {
          size_t idx = ((size_t)((m >> 9) * 8 + (n >> 7))) * 65536 +
                       (size_t)(n & 127) * 512 + (m & 511);
          obf[idx] = (__bf16)v;
        }
      }
    }
  }
}

// ---------------- output projection (MODE2), unchanged structure ----------------
__global__ __launch_bounds__(512, 2) void gemm_outproj(
    const __bf16* __restrict__ A, const __bf16* __restrict__ Bw,
    const float* __restrict__ bias, float* __restrict__ of32) {
  __shared__ alignas(16) __bf16 As0[256 * 64];
  __shared__ alignas(16) __bf16 Bs0[256 * 64];
  __shared__ alignas(16) __bf16 As1[256 * 64];
  __shared__ alignas(16) __bf16 Bs1[256 * 64];
  const int tid = threadIdx.x;
  const int lane = tid & 63;
  const int wave = tid >> 6;
  const int bm = blockIdx.x, bn = blockIdx.y;

  GemmCore core{A + (size_t)bm * 256 * 1024, Bw + (size_t)bn * 256 * 1024,
                As0, Bs0, As1, Bs1,
                tid, lane, wave >> 2, wave & 3, lane & 15, lane >> 4,
                tid >> 3, (tid & 7) ^ ((tid >> 3) & 7)};

  f32x4 acc[8][4];
#pragma unroll
  for (int mi = 0; mi < 8; ++mi)
#pragma unroll
    for (int ni = 0; ni < 4; ++ni)
#pragma unroll
      for (int e = 0; e < 4; ++e) acc[mi][ni][e] = 0.f;

  core.run(acc);

  const int wr = wave >> 2, wc = wave & 3, lr = lane & 15, khi = lane >> 4;
#pragma unroll
  for (int mi = 0; mi < 8; ++mi) {
#pragma unroll
    for (int ni = 0; ni < 4; ++ni) {
      const int n = bn * 256 + wc * 64 + ni * 16 + lr;
#pragma unroll
      for (int r = 0; r < 4; ++r) {
        const int m = bm * 256 + wr * 128 + mi * 16 + khi * 4 + r;
        of32[(size_t)m * 1024 + n] = acc[mi][ni][r] + bias[n];
      }
    }
  }
}

// ---------------- adj: per-head column softmax, x1e4, CENTERED bf16, TRANSPOSED ----------------
__global__ __launch_bounds__(256) void adj_kernel(const float* __restrict__ ch_all,
                                                  const float* __restrict__ ct_all,
                                                  __bf16* __restrict__ adjT) {
  const int wave = threadIdx.x >> 6, lane = threadIdx.x & 63;
  const int row = blockIdx.x * 4 + wave;  // 0..4095
  const int h = row >> 9, i = row & 511;
  float ch[18];
  const float* chp = ch_all + ((size_t)h * 512 + i) * 18;
#pragma unroll
  for (int t = 0; t < 18; ++t) ch[t] = chp[t];
  float e[8];
  float m = -1e30f;
#pragma unroll
  for (int jj = 0; jj < 8; ++jj) {
    const int j = jj * 64 + lane;
    const float* ctp = ct_all + ((size_t)h * 512 + j) * 18;
    float d = 0.f;
#pragma unroll
    for (int t = 0; t < 18; ++t) d += ch[t] * ctp[t];
    if (j == i) d = 0.f;
    e[jj] = d;
    m = fmaxf(m, d);
  }
#pragma unroll
  for (int off = 32; off >= 1; off >>= 1) m = fmaxf(m, __shfl_xor(m, off));
  float s = 0.f;
#pragma unroll
  for (int jj = 0; jj < 8; ++jj) { e[jj] = __expf(e[jj] - m); s += e[jj]; }
#pragma unroll
  for (int off = 32; off >= 1; off >>= 1) s += __shfl_xor(s, off);
  const float inv = 10000.f / s;
  __bf16* op = adjT + (size_t)h * 262144 + i;  // column i of [512][512]
#pragma unroll
  for (int jj = 0; jj < 8; ++jj)
    op[(size_t)(jj * 64 + lane) * 512] = (__bf16)(e[jj] * inv - 19.53125f);
}

// ---------------- fused attention core (unchanged from round 10: ~150 us) ----------------
__global__ __launch_bounds__(256, 2) void fused_attn_kernel(
    const __bf16* __restrict__ fh, const __bf16* __restrict__ ft,
    const __bf16* __restrict__ fvT, const __bf16* __restrict__ adjT,
    float* __restrict__ fr, __bf16* __restrict__ ctx) {
  __shared__ alignas(16) __bf16 Bt0[128 * 128];   // 32 KB
  __shared__ alignas(16) __bf16 Bt1[128 * 128];   // 32 KB
  __shared__ alignas(16) __bf16 Pl[4][16 * 128];  // 16 KB, per-wave P chunk
  const int tid = threadIdx.x;
  const int l = tid & 63, w = tid >> 6;
  const int b = blockIdx.x;            // 0..31 -> XCD = b&7
  const int h = blockIdx.y >> 3;       // 0..7
  const int qt = blockIdx.y & 7;       // 0..7
  const int bh = b * 8 + h;
  const int wrow = qt * 64 + w * 16;
  const int lr = l & 15;
  const int khi = l >> 4;  // 0..3

  const int srow = tid >> 4;                 // row within 16-row group
  const int scc = (tid & 15) ^ (srow & 7);   // pre-swizzled source chunk

  bf8 afr[4];
  {
    const __bf16* ap = fh + (size_t)bh * 65536 + (size_t)(wrow + lr) * 128 + khi * 8;
#pragma unroll
    for (int kk4 = 0; kk4 < 4; ++kk4)
      afr[kk4] = *reinterpret_cast<const bf8*>(ap + kk4 * 32);
  }

  const __bf16* ftb = ft + (size_t)bh * 65536;
  const __bf16* fvb = fvT + (size_t)bh * 65536;

  auto stage_ft = [&](__bf16* dst, int kt) {
#pragma unroll
    for (int i = 0; i < 8; ++i)
      gload_lds16(ftb + (size_t)(kt * 128 + i * 16 + srow) * 128 + scc * 8,
                  dst + i * 2048 + tid * 8);
  };
  auto stage_fv = [&](__bf16* dst, int kt) {
#pragma unroll
    for (int i = 0; i < 8; ++i)
      gload_lds16(fvb + (size_t)(i * 16 + srow) * 512 + kt * 128 + scc * 8,
                  dst + i * 2048 + tid * 8);
  };

  f32x4 acc[32];
#pragma unroll
  for (int n = 0; n < 32; ++n)
#pragma unroll
    for (int e = 0; e < 4; ++e) acc[n][e] = 0.f;

  // ---- phase 1: S = fh . ft^T, 2-deep pipelined ----
  stage_ft(Bt0, 0);
  stage_ft(Bt1, 1);
#pragma unroll
  for (int kt = 0; kt < 4; ++kt) {
    __bf16* B = (kt & 1) ? Bt1 : Bt0;
    WAITV(8);
    BARRIER();
    __builtin_amdgcn_s_setprio(1);
#pragma unroll
    for (int kk4 = 0; kk4 < 4; ++kk4) {
      bf8 bfr[8];
#pragma unroll
      for (int n2 = 0; n2 < 8; ++n2)
        bfr[n2] = *reinterpret_cast<const bf8*>(
            &B[(n2 * 16 + lr) * 128 + ((kk4 * 4 + khi) ^ (lr & 7)) * 8]);
#pragma unroll
      for (int n2 = 0; n2 < 8; ++n2)
        acc[kt * 8 + n2] =
            __builtin_amdgcn_mfma_f32_16x16x32_bf16(afr[kk4], bfr[n2], acc[kt * 8 + n2], 0, 0, 0);
    }
    __builtin_amdgcn_s_setprio(0);
    BARRIER();
    if (kt == 0) stage_ft(Bt0, 2);
    else if (kt == 1) stage_ft(Bt1, 3);
    else if (kt == 2) stage_fv(Bt0, 0);
    else stage_fv(Bt1, 1);
  }

  // ---- phase 2: logits + in-register row softmax (fv0/fv1 in flight) ----
  const float scale = 0.08838834764831845f;  // 1/sqrt(128)
  const __bf16* adjTp = adjT + (size_t)h * 262144;
  float mrow[4] = {-1e30f, -1e30f, -1e30f, -1e30f};
#pragma unroll
  for (int n = 0; n < 32; ++n) {
    const int col = n * 16 + lr;
    bf4 av4 = *reinterpret_cast<const bf4*>(adjTp + (size_t)col * 512 + wrow + khi * 4);
#pragma unroll
    for (int r = 0; r < 4; ++r) {
      float v = acc[n][r] * scale + (float)av4[r];
      acc[n][r] = v;
      mrow[r] = fmaxf(mrow[r], v);
    }
  }
#pragma unroll
  for (int r = 0; r < 4; ++r)
#pragma unroll
    for (int off = 1; off <= 8; off <<= 1) mrow[r] = fmaxf(mrow[r], __shfl_xor(mrow[r], off));
  float srw[4] = {0.f, 0.f, 0.f, 0.f};
#pragma unroll
  for (int n = 0; n < 32; ++n)
#pragma unroll
    for (int r = 0; r < 4; ++r) {
      float e = __expf(acc[n][r] - mrow[r]);
      acc[n][r] = e;
      srw[r] += e;
    }
#pragma unroll
  for (int r = 0; r < 4; ++r)
#pragma unroll
    for (int off = 1; off <= 8; off <<= 1) srw[r] += __shfl_xor(srw[r], off);
  float inv[4];
#pragma unroll
  for (int r = 0; r < 4; ++r) inv[r] = 1.f / srw[r];
#pragma unroll
  for (int n = 0; n < 32; ++n)
#pragma unroll
    for (int r = 0; r < 4; ++r) acc[n][r] *= inv[r];

  // write fr (required output), once
  {
    float* frb = fr + (size_t)bh * 262144;
#pragma unroll
    for (int n = 0; n < 32; ++n) {
      const int col = n * 16 + lr;
#pragma unroll
      for (int r = 0; r < 4; ++r)
        frb[(size_t)(wrow + khi * 4 + r) * 512 + col] = acc[n][r];
    }
  }

  // ---- phase 3: PV, 2-deep pipelined ----
  f32x4 acc2[8];
#pragma unroll
  for (int n2 = 0; n2 < 8; ++n2)
#pragma unroll
    for (int e = 0; e < 4; ++e) acc2[n2][e] = 0.f;

  __bf16* Pw = &Pl[w][0];
#pragma unroll
  for (int kt = 0; kt < 4; ++kt) {
    __bf16* B = (kt & 1) ? Bt1 : Bt0;
#pragma unroll
    for (int n2 = 0; n2 < 8; ++n2) {
      const int colc = n2 * 2 + (lr >> 3);
      const int cl = lr & 7;
#pragma unroll
      for (int r = 0; r < 4; ++r) {
        const int q = khi * 4 + r;
        Pw[q * 128 + ((colc ^ (q & 7)) * 8) + cl] = (__bf16)acc[kt * 8 + n2][r];
      }
    }
    LGKM0();
    if (kt < 3) { WAITV(8); } else { WAITV(0); }
    BARRIER();
    __builtin_amdgcn_s_setprio(1);
#pragma unroll
    for (int kk4 = 0; kk4 < 4; ++kk4) {
      bf8 pa = *reinterpret_cast<const bf8*>(
          &Pw[lr * 128 + ((kk4 * 4 + khi) ^ (lr & 7)) * 8]);
      bf8 bfr[8];
#pragma unroll
      for (int n2 = 0; n2 < 8; ++n2)
        bfr[n2] = *reinterpret_cast<const bf8*>(
            &B[(n2 * 16 + lr) * 128 + ((kk4 * 4 + khi) ^ (lr & 7)) * 8]);
#pragma unroll
      for (int n2 = 0; n2 < 8; ++n2)
        acc2[n2] = __builtin_amdgcn_mfma_f32_16x16x32_bf16(pa, bfr[n2], acc2[n2], 0, 0, 0);
    }
    __builtin_amdgcn_s_setprio(0);
    if (kt < 3) {
      BARRIER();
      if (kt == 0) stage_fv(Bt0, 2);
      else if (kt == 1) stage_fv(Bt1, 3);
    }
  }

#pragma unroll
  for (int n2 = 0; n2 < 8; ++n2) {
    const int c = n2 * 16 + lr;
#pragma unroll
    for (int r = 0; r < 4; ++r) {
      const int q = wrow + khi * 4 + r;
      ctx[(size_t)(b * 512 + q) * 1024 + h * 128 + c] = (__bf16)acc2[n2][r];
    }
  }
}

extern "C" void kernel_launch(void* const* d_in, const int* in_sizes, int n_in,
                              void* d_out, int out_size, void* d_ws, size_t ws_size,
                              hipStream_t stream) {
  const float* x_q  = (const float*)d_in[0];
  const float* x_kv = (const float*)d_in[1];
  const float* Wh   = (const float*)d_in[2];
  const float* bh   = (const float*)d_in[3];
  const float* Wv   = (const float*)d_in[4];
  const float* bv   = (const float*)d_in[5];
  const float* Wo   = (const float*)d_in[6];
  const float* bo   = (const float*)d_in[7];
  const float* rel  = (const float*)d_in[8];
  const float* colh = (const float*)d_in[9];
  const float* colt = (const float*)d_in[10];

  float* out = (float*)d_out;
  float* fr  = out + 16777216;  // 32*512*1024 floats, then 256*512*512 floats

  __bf16* xq_bf  = (__bf16*)d_ws;
  __bf16* xkv_bf = xq_bf + 16777216;
  __bf16* Wh_bf  = xkv_bf + 16777216;
  __bf16* Wv_bf  = Wh_bf + 1048576;
  __bf16* Wo_bf  = Wv_bf + 1048576;
  __bf16* fhead  = Wo_bf + 1048576;
  __bf16* ftail  = fhead + 16777216;
  __bf16* fvT    = ftail + 16777216;
  __bf16* adjT   = fvT + 16777216;
  __bf16* ctx    = adjT + 2097152;

  cvt_kernel<<<4096, 256, 0, stream>>>(x_q, xq_bf, 4194304);
  cvt_kernel<<<4096, 256, 0, stream>>>(x_kv, xkv_bf, 4194304);
  cvt3_kernel<<<768, 256, 0, stream>>>(Wh, Wv, Wo, Wh_bf, Wv_bf, Wo_bf);

  gemm_inproj<<<dim3(64, 4, 3), 512, 0, stream>>>(xq_bf, xkv_bf, Wh_bf, Wv_bf,
                                                  bh, bv, rel, fhead, ftail, fvT);

  adj_kernel<<<1024, 256, 0, stream>>>(colh, colt, adjT);

  fused_attn_kernel<<<dim3(32, 64), 256, 0, stream>>>(fhead, ftail, fvT, adjT, fr, ctx);

  gemm_outproj<<<dim3(64, 4), 512, 0, stream>>>(ctx, Wo_bf, bo, out);
}